// Round 16
// baseline (557.431 us; speedup 1.0000x reference)
//
#include <hip/hip_runtime.h>
#include <math.h>

// Max-plus DP: out[b,t,k] = x[b,t,k] + max(out[b,t-1,k], out[b,t-1,k-1])
// 32 batches x 8 column groups = 256 blocks; 4 specialized waves/block
// (w0=DP, w1=stager, w2/3=storers) — round-15-verified skeleton (255us).
//
// Round-16 change: remove the LAST two in-loop drains (both had >=1 tile
// of natural slack they weren't using):
//  - stager: xbuf tri-buffered; at tile r stage tile r+2 then vmcnt(16)
//    (waits only tile r+1's 16 loads; steady-state ~free). Tail: vmcnt(0)
//    with a tile of slack.
//  - DP: flag=r (tiles <= r-1 readable) published with a COUNTED wait:
//    after store(r), vmcnt(3) [g>=1: outstanding = bnxt,fpre,store(r);
//    spin loads always retire before this point] or vmcnt(1) [g=0] forces
//    only store(r-1) complete — issued one full tile earlier. Consumer
//    lag 1->2 tiles (chain 64+14 steps), paid for by the shorter tile.
// Sync stays raw s_barrier + lgkmcnt(0) (never __syncthreads). Row body,
// staging addressing, bndv build, bws/flags protocol: r15-verified.

#define BB 32
#define TT 2048
#define KK 1024
#define GG 8
#define WW (KK / GG)      // 128 cols per group
#define RR 32             // rows per tile (flag granularity)
#define HH 16             // half-tile rows (obuf ring granularity)
#define NT (TT / RR)      // 64 tiles

typedef __attribute__((address_space(1))) void GV;  // global
typedef __attribute__((address_space(3))) void LV;  // LDS

#define BAR() do {                                              \
    __asm__ volatile("s_waitcnt lgkmcnt(0)" ::: "memory");      \
    __builtin_amdgcn_s_barrier();                               \
    __builtin_amdgcn_sched_barrier(0);                          \
} while (0)

__global__ __launch_bounds__(256, 1)
void harddtw_ws2(const float* __restrict__ x, float* __restrict__ out,
                 int* __restrict__ flags, float* __restrict__ bws)
{
    const int bid  = blockIdx.x;
    const int g    = bid >> 5;           // column group 0..7
    const int b    = bid & 31;           // batch
    const int w    = threadIdx.x >> 6;   // 0=DP 1=stager 2,3=storer
    const int lane = threadIdx.x & 63;
    const bool lz  = (lane == 0);

    const int k0 = g * WW;
    const int kc = k0 + (lane << 1);
    const size_t base = (size_t)b * TT * KK;

    int* myflag = flags + bid;
    int* upflag = flags + bid - 32;      // same batch, group g-1
    float*       mybw = bws + ((size_t)(b * GG + g)) * TT;       // publish
    const float* upbw = bws + ((size_t)(b * GG + g - 1)) * TT;   // consume

    __shared__ float xbuf[3][RR * WW];   // 3 x 16KB input tiles (tri-buffer)
    __shared__ float obuf[2][HH * WW];   // 2 x 8KB output half-tiles

    // Staging addressing (r8-verified): inst i stages rows 2i,2i+1; lane l
    // covers row 2i+(l>>5), float cols [4*(l&31), +4).
    const float* xstage = x + base + k0 + (size_t)(lane >> 5) * KK
                          + ((lane & 31) << 2);

    const bool pub = (g < GG - 1);

    float pv0 = 0.0f, pv1 = 0.0f;        // prev-row values (0 => row0 = x)
    float sh_prev = 0.0f;                // left-neighbor pv1 from "row -1"
    float bcur = -INFINITY, bnxt = -INFINITY;
    int   bndv = 0;                      // lane j = row j's boundary (built)
    int   fpre = 0;                      // prefetched upflag value

    if (w == 1) {                        // prologue: stage tiles 0 and 1
#pragma unroll
        for (int t = 0; t < 2; ++t) {
            const float* gp = xstage + (size_t)t * RR * KK;
#pragma unroll
            for (int i = 0; i < RR / 2; ++i) {
                __builtin_amdgcn_global_load_lds(
                    (GV*)(void*)gp, (LV*)(void*)&xbuf[t][i * 256], 16, 0, 0);
                gp += 2 * KK;
            }
        }
        __asm__ volatile("s_waitcnt vmcnt(0)" ::: "memory");
    }
    if (w == 0 && g > 0) {               // tile-0 boundary
        while (__hip_atomic_load(upflag, __ATOMIC_RELAXED,
                                 __HIP_MEMORY_SCOPE_AGENT) < 1)
            __builtin_amdgcn_s_sleep(1);
        __asm__ volatile("" ::: "memory");
        if (lz) bcur = 0.0f;             // virtual row -1
        else if (lane < RR)
            bcur = __hip_atomic_load(upbw + lane - 1, __ATOMIC_RELAXED,
                                     __HIP_MEMORY_SCOPE_AGENT);
    }
    BAR();                               // xbuf[0..1] ready for all

#pragma unroll 1
    for (int r = 0; r < NT; ++r) {
        const int cur = r % 3;

        // ================= phase 1 =================
        if (w == 0) {
            float2 td[HH];               // rows 0..15 of tile r
#pragma unroll
            for (int j = 0; j < HH; ++j)
                td[j] = *(const float2*)&xbuf[cur][j * WW + (lane << 1)];
            __builtin_amdgcn_sched_barrier(0);
            float2 ov[HH];
#pragma unroll
            for (int j = 0; j < HH; ++j) {
                float2 xv = td[j];
                float n1 = xv.y + fmaxf(pv1, pv0);
                float sh_new = __shfl_up(n1, 1);       // consumed next row
                float bv = __int_as_float(
                    __builtin_amdgcn_readlane(__float_as_int(bcur), j));
                float left = lz ? bv : sh_prev;
                float n0 = xv.x + fmaxf(pv0, left);
                ov[j].x = n0; ov[j].y = n1;
                {   // lane j records row j's boundary value
                    int b63 = __builtin_amdgcn_readlane(__float_as_int(n1), 63);
                    if (lane == j) bndv = b63;
                }
                pv0 = n0; pv1 = n1; sh_prev = sh_new;
            }
#pragma unroll
            for (int j = 0; j < HH; ++j)
                *(float2*)&obuf[0][j * WW + (lane << 1)] = ov[j];
        } else if (w >= 2 && r > 0) {
            // store h1 of tile r-1
            const int sw = w - 2;
            float* ob = out + base
                      + (size_t)((r - 1) * RR + HH + sw * 8) * KK + kc;
#pragma unroll
            for (int i = 0; i < 8; ++i) {
                float2 v = *(const float2*)&obuf[1][(sw * 8 + i) * WW
                                                    + (lane << 1)];
                *(float2*)ob = v;
                ob += KK;
            }
        }
        BAR();

        // ================= phase 2 =================
        if (w == 0) {
            float2 td[HH];               // rows 16..31 of tile r
#pragma unroll
            for (int j = 0; j < HH; ++j)
                td[j] = *(const float2*)&xbuf[cur][(HH + j) * WW + (lane << 1)];
            __builtin_amdgcn_sched_barrier(0);
            float2 ov[HH];
#pragma unroll
            for (int j = 0; j < HH; ++j) {
                float2 xv = td[j];
                float n1 = xv.y + fmaxf(pv1, pv0);
                float sh_new = __shfl_up(n1, 1);
                float bv = __int_as_float(
                    __builtin_amdgcn_readlane(__float_as_int(bcur), HH + j));
                float left = lz ? bv : sh_prev;
                float n0 = xv.x + fmaxf(pv0, left);
                ov[j].x = n0; ov[j].y = n1;
                {
                    int b63 = __builtin_amdgcn_readlane(__float_as_int(n1), 63);
                    if (lane == HH + j) bndv = b63;
                }
                pv0 = n0; pv1 = n1; sh_prev = sh_new;
            }
#pragma unroll
            for (int j = 0; j < HH; ++j)
                *(float2*)&obuf[1][j * WW + (lane << 1)] = ov[j];

            if (pub) {
                // boundary store for tile r (one wave-wide agent store)
                if (lane < RR)
                    __hip_atomic_store(mybw + (size_t)r * RR + lane,
                                       __int_as_float(bndv),
                                       __ATOMIC_RELAXED,
                                       __HIP_MEMORY_SCOPE_AGENT);
                // flag = r (tiles <= r-1 readable): COUNTED wait forces
                // only store(r-1) [issued a full tile ago] complete.
                // Outstanding now: g>0: {bnxt, fpre, store(r)} = 3
                // (spin loads always retired); g==0: {store(r)} = 1.
                if (r > 0) {
                    if (g > 0)
                        __asm__ volatile("s_waitcnt vmcnt(3)" ::: "memory");
                    else
                        __asm__ volatile("s_waitcnt vmcnt(1)" ::: "memory");
                    if (lz)
                        __hip_atomic_store(myflag, r, __ATOMIC_RELAXED,
                                           __HIP_MEMORY_SCOPE_AGENT);
                }
            }
            // next tile's boundary (fpre-guarded spin, then loads)
            if (g > 0 && r < NT - 1) {
                if (fpre < r + 2) {
                    while (__hip_atomic_load(upflag, __ATOMIC_RELAXED,
                                             __HIP_MEMORY_SCOPE_AGENT) < r + 2)
                        __builtin_amdgcn_s_sleep(1);
                }
                __asm__ volatile("" ::: "memory");
                if (lane < RR)
                    bnxt = __hip_atomic_load(
                               upbw + (size_t)(r + 1) * RR + lane - 1,
                               __ATOMIC_RELAXED, __HIP_MEMORY_SCOPE_AGENT);
                fpre = __hip_atomic_load(upflag, __ATOMIC_RELAXED,
                                         __HIP_MEMORY_SCOPE_AGENT);
            }
            bcur = bnxt;
        } else if (w == 1) {
            if (r < NT - 2) {
                // stage tile r+2 into xbuf[(r+2)%3]; counted wait ensures
                // tile r+1 (consumed next tile) is resident. ~free.
                const float* gp = xstage + (size_t)(r + 2) * RR * KK;
                float* lp = &xbuf[(r + 2) % 3][0];
#pragma unroll
                for (int i = 0; i < RR / 2; ++i) {
                    __builtin_amdgcn_global_load_lds(
                        (GV*)(void*)gp, (LV*)(void*)(lp + i * 256), 16, 0, 0);
                    gp += 2 * KK;
                }
                __asm__ volatile("s_waitcnt vmcnt(16)" ::: "memory");
            } else {
                // tail: last pending tile's loads were issued >=1 tile ago
                __asm__ volatile("s_waitcnt vmcnt(0)" ::: "memory");
            }
        } else if (w >= 2) {
            // store h0 of tile r
            const int sw = w - 2;
            float* ob = out + base + (size_t)(r * RR + sw * 8) * KK + kc;
#pragma unroll
            for (int i = 0; i < 8; ++i) {
                float2 v = *(const float2*)&obuf[0][(sw * 8 + i) * WW
                                                    + (lane << 1)];
                *(float2*)ob = v;
                ob += KK;
            }
        }
        BAR();
    }

    // tail: store h1 of last tile; publish terminal flag = NT.
    if (w >= 2) {
        const int sw = w - 2;
        float* ob = out + base
                  + (size_t)((NT - 1) * RR + HH + sw * 8) * KK + kc;
#pragma unroll
        for (int i = 0; i < 8; ++i) {
            float2 v = *(const float2*)&obuf[1][(sw * 8 + i) * WW
                                                + (lane << 1)];
            *(float2*)ob = v;
            ob += KK;
        }
    }
    if (w == 0 && pub) {
        __asm__ volatile("s_waitcnt vmcnt(0)" ::: "memory");
        if (lz)
            __hip_atomic_store(myflag, NT, __ATOMIC_RELAXED,
                               __HIP_MEMORY_SCOPE_AGENT);
    }
}

extern "C" void kernel_launch(void* const* d_in, const int* in_sizes, int n_in,
                              void* d_out, int out_size, void* d_ws, size_t ws_size,
                              hipStream_t stream) {
    (void)in_sizes; (void)n_in; (void)out_size; (void)ws_size;
    const float* x = (const float*)d_in[0];
    float* out = (float*)d_out;
    int* flags = (int*)d_ws;
    float* bws = (float*)((char*)d_ws + 4096);  // [32*8][2048] floats = 2MB

    // ws is re-poisoned to 0xAA before every timed launch; flags must be 0.
    // bws needs no init: every read is flag-gated behind its producer.
    (void)hipMemsetAsync(flags, 0, BB * GG * sizeof(int), stream);

    harddtw_ws2<<<dim3(BB * GG), dim3(256), 0, stream>>>(x, out, flags, bws);
}

// Round 17
// 515.754 us; speedup vs baseline: 1.0808x; 1.0808x over previous
//
#include <hip/hip_runtime.h>
#include <math.h>

// Max-plus DP: out[b,t,k] = x[b,t,k] + max(out[b,t-1,k], out[b,t-1,k-1])
// 32 batches x 8 column groups = 256 blocks; 4 specialized waves/block
// (w0=DP, w1=stager, w2/3=storers) — round-15-verified skeleton (255us).
//
// Round-17 change: RR 32 -> 64 (ONE variable). Total = chain_steps x
// T_tile = (2048/RR + 2*(GG-1)) x (F + RR*r). Rounds 5-16 varied every
// component of F (drains, DS queue, schedule, publish path) and of r
// (shfl vs DPP) with T_tile ~ 8Kcy invariant — but RR itself was never
// varied. RR=64 halves the chain (78 -> 46 steps) and amortizes F over
// 2x rows. Clean diagnostic: F-dominated -> ~180us; r-dominated -> ~255
// (null redirects round 18 at per-row cost).
// Bonus fit: boundary vector now spans all 64 lanes (lane j = row j).
// LDS 96KB (xbuf 2x32K, obuf 2x16K). Everything else byte-identical.

#define BB 32
#define TT 2048
#define KK 1024
#define GG 8
#define WW (KK / GG)      // 128 cols per group
#define RR 64             // rows per tile (flag granularity)
#define HH 32             // half-tile rows (obuf ring granularity)
#define NT (TT / RR)      // 32 tiles

typedef __attribute__((address_space(1))) void GV;  // global
typedef __attribute__((address_space(3))) void LV;  // LDS

#define BAR() do {                                              \
    __asm__ volatile("s_waitcnt lgkmcnt(0)" ::: "memory");      \
    __builtin_amdgcn_s_barrier();                               \
    __builtin_amdgcn_sched_barrier(0);                          \
} while (0)

__global__ __launch_bounds__(256, 1)
void harddtw_r64(const float* __restrict__ x, float* __restrict__ out,
                 int* __restrict__ flags, float* __restrict__ bws)
{
    const int bid  = blockIdx.x;
    const int g    = bid >> 5;           // column group 0..7
    const int b    = bid & 31;           // batch
    const int w    = threadIdx.x >> 6;   // 0=DP 1=stager 2,3=storer
    const int lane = threadIdx.x & 63;
    const bool lz  = (lane == 0);

    const int k0 = g * WW;
    const int kc = k0 + (lane << 1);
    const size_t base = (size_t)b * TT * KK;

    int* myflag = flags + bid;
    int* upflag = flags + bid - 32;      // same batch, group g-1
    float*       mybw = bws + ((size_t)(b * GG + g)) * TT;       // publish
    const float* upbw = bws + ((size_t)(b * GG + g - 1)) * TT;   // consume

    __shared__ float xbuf[2][RR * WW];   // 2 x 32KB input tiles
    __shared__ float obuf[2][HH * WW];   // 2 x 16KB output half-tiles

    // Staging addressing (r8-verified): inst i stages rows 2i,2i+1; lane l
    // covers row 2i+(l>>5), float cols [4*(l&31), +4).
    const float* xstage = x + base + k0 + (size_t)(lane >> 5) * KK
                          + ((lane & 31) << 2);

    const bool pub = (g < GG - 1);

    float pv0 = 0.0f, pv1 = 0.0f;        // prev-row values (0 => row0 = x)
    float sh_prev = 0.0f;                // left-neighbor pv1 from "row -1"
    float bcur = -INFINITY, bnxt = -INFINITY;  // lane j = row j's boundary
    int   bndv = 0;                      // lane j = row j's boundary (built)
    int   fpre = 0;                      // prefetched upflag value

    if (w == 1) {                        // stage tile 0
        const float* gp = xstage;
#pragma unroll
        for (int i = 0; i < RR / 2; ++i) {
            __builtin_amdgcn_global_load_lds((GV*)(void*)gp,
                                             (LV*)(void*)&xbuf[0][i * 256],
                                             16, 0, 0);
            gp += 2 * KK;
        }
        __asm__ volatile("s_waitcnt vmcnt(0)" ::: "memory");
    }
    if (w == 0 && g > 0) {               // tile-0 boundary
        while (__hip_atomic_load(upflag, __ATOMIC_RELAXED,
                                 __HIP_MEMORY_SCOPE_AGENT) < 1)
            __builtin_amdgcn_s_sleep(1);
        __asm__ volatile("" ::: "memory");
        if (lz) bcur = 0.0f;             // virtual row -1
        else
            bcur = __hip_atomic_load(upbw + lane - 1, __ATOMIC_RELAXED,
                                     __HIP_MEMORY_SCOPE_AGENT);
    }
    BAR();                               // xbuf[0] ready for all

#pragma unroll 1
    for (int r = 0; r < NT; ++r) {
        const int cur = r & 1;

        // ================= phase 1 (rows 0..31) =================
        if (w == 0) {
            float2 td[HH];
#pragma unroll
            for (int j = 0; j < HH; ++j)
                td[j] = *(const float2*)&xbuf[cur][j * WW + (lane << 1)];
            __builtin_amdgcn_sched_barrier(0);
            float2 ov[HH];
#pragma unroll
            for (int j = 0; j < HH; ++j) {
                float2 xv = td[j];
                float n1 = xv.y + fmaxf(pv1, pv0);
                float sh_new = __shfl_up(n1, 1);       // consumed next row
                float bv = __int_as_float(
                    __builtin_amdgcn_readlane(__float_as_int(bcur), j));
                float left = lz ? bv : sh_prev;
                float n0 = xv.x + fmaxf(pv0, left);
                ov[j].x = n0; ov[j].y = n1;
                {   // lane j records row j's boundary value
                    int b63 = __builtin_amdgcn_readlane(__float_as_int(n1), 63);
                    if (lane == j) bndv = b63;
                }
                pv0 = n0; pv1 = n1; sh_prev = sh_new;
            }
#pragma unroll
            for (int j = 0; j < HH; ++j)
                *(float2*)&obuf[0][j * WW + (lane << 1)] = ov[j];
        } else if (w >= 2 && r > 0) {
            // store h1 of tile r-1 (rows 32..63)
            const int sw = w - 2;
            float* ob = out + base
                      + (size_t)((r - 1) * RR + HH + sw * 16) * KK + kc;
#pragma unroll
            for (int i = 0; i < 16; ++i) {
                float2 v = *(const float2*)&obuf[1][(sw * 16 + i) * WW
                                                    + (lane << 1)];
                *(float2*)ob = v;
                ob += KK;
            }
        }
        BAR();

        // ================= phase 2 (rows 32..63) =================
        if (w == 0) {
            float2 td[HH];
#pragma unroll
            for (int j = 0; j < HH; ++j)
                td[j] = *(const float2*)&xbuf[cur][(HH + j) * WW + (lane << 1)];
            __builtin_amdgcn_sched_barrier(0);
            float2 ov[HH];
#pragma unroll
            for (int j = 0; j < HH; ++j) {
                float2 xv = td[j];
                float n1 = xv.y + fmaxf(pv1, pv0);
                float sh_new = __shfl_up(n1, 1);
                float bv = __int_as_float(
                    __builtin_amdgcn_readlane(__float_as_int(bcur), HH + j));
                float left = lz ? bv : sh_prev;
                float n0 = xv.x + fmaxf(pv0, left);
                ov[j].x = n0; ov[j].y = n1;
                {
                    int b63 = __builtin_amdgcn_readlane(__float_as_int(n1), 63);
                    if (lane == HH + j) bndv = b63;
                }
                pv0 = n0; pv1 = n1; sh_prev = sh_new;
            }
#pragma unroll
            for (int j = 0; j < HH; ++j)
                *(float2*)&obuf[1][j * WW + (lane << 1)] = ov[j];

            // publish: ONE wave-wide boundary store (64 rows), drain, flag.
            if (pub) {
                __hip_atomic_store(mybw + (size_t)r * RR + lane,
                                   __int_as_float(bndv),
                                   __ATOMIC_RELAXED,
                                   __HIP_MEMORY_SCOPE_AGENT);
                __asm__ volatile("s_waitcnt vmcnt(0)" ::: "memory");
                if (lz)
                    __hip_atomic_store(myflag, r + 1, __ATOMIC_RELAXED,
                                       __HIP_MEMORY_SCOPE_AGENT);
            }
            // next tile's boundary (fpre-guarded spin; r8-verified)
            if (g > 0 && r < NT - 1) {
                if (fpre < r + 2) {
                    while (__hip_atomic_load(upflag, __ATOMIC_RELAXED,
                                             __HIP_MEMORY_SCOPE_AGENT) < r + 2)
                        __builtin_amdgcn_s_sleep(1);
                }
                __asm__ volatile("" ::: "memory");
                // lane j -> row (r+1)*64 + j - 1 of producer's boundary col
                bnxt = __hip_atomic_load(
                           upbw + (size_t)(r + 1) * RR + lane - 1,
                           __ATOMIC_RELAXED, __HIP_MEMORY_SCOPE_AGENT);
                fpre = __hip_atomic_load(upflag, __ATOMIC_RELAXED,
                                         __HIP_MEMORY_SCOPE_AGENT);
            }
            bcur = bnxt;
        } else if (w == 1) {
            if (r < NT - 1) {            // stage tile r+1
                const float* gp = xstage + (size_t)(r + 1) * RR * KK;
                float* lp = &xbuf[cur ^ 1][0];
#pragma unroll
                for (int i = 0; i < RR / 2; ++i) {
                    __builtin_amdgcn_global_load_lds((GV*)(void*)gp,
                                                     (LV*)(void*)(lp + i * 256),
                                                     16, 0, 0);
                    gp += 2 * KK;
                }
                __asm__ volatile("s_waitcnt vmcnt(0)" ::: "memory");
            }
        } else if (w >= 2) {
            // store h0 of tile r (rows 0..31)
            const int sw = w - 2;
            float* ob = out + base + (size_t)(r * RR + sw * 16) * KK + kc;
#pragma unroll
            for (int i = 0; i < 16; ++i) {
                float2 v = *(const float2*)&obuf[0][(sw * 16 + i) * WW
                                                    + (lane << 1)];
                *(float2*)ob = v;
                ob += KK;
            }
        }
        BAR();
    }

    // tail: store h1 of the last tile
    if (w >= 2) {
        const int sw = w - 2;
        float* ob = out + base
                  + (size_t)((NT - 1) * RR + HH + sw * 16) * KK + kc;
#pragma unroll
        for (int i = 0; i < 16; ++i) {
            float2 v = *(const float2*)&obuf[1][(sw * 16 + i) * WW
                                                + (lane << 1)];
            *(float2*)ob = v;
            ob += KK;
        }
    }
}

extern "C" void kernel_launch(void* const* d_in, const int* in_sizes, int n_in,
                              void* d_out, int out_size, void* d_ws, size_t ws_size,
                              hipStream_t stream) {
    (void)in_sizes; (void)n_in; (void)out_size; (void)ws_size;
    const float* x = (const float*)d_in[0];
    float* out = (float*)d_out;
    int* flags = (int*)d_ws;
    float* bws = (float*)((char*)d_ws + 4096);  // [32*8][2048] floats = 2MB

    // ws is re-poisoned to 0xAA before every timed launch; flags must be 0.
    // bws needs no init: every read is flag-gated behind its producer.
    (void)hipMemsetAsync(flags, 0, BB * GG * sizeof(int), stream);

    harddtw_r64<<<dim3(BB * GG), dim3(256), 0, stream>>>(x, out, flags, bws);
}